// Round 1
// baseline (5791.403 us; speedup 1.0000x reference)
//
#include <hip/hip_runtime.h>

#define BATCH 64
#define SEQ 8192
#define RDIM 80
#define RING 169          // max delay 168 + 1
#define LEAK 0.3f
#define OMLEAK 0.7f

// taps: 1, 4, 24, 96, 168
__device__ __forceinline__ float fast_tanh(float z) {
    // tanh(z) = 1 - 2/(exp(2z)+1); exact saturation at +-inf, abs err ~1e-7
    float e = __expf(2.0f * z);
    return 1.0f - 2.0f / (e + 1.0f);
}

__global__ __launch_bounds__(256, 1)
void reservoir_kernel(const float* __restrict__ x,
                      const float* __restrict__ W_in,
                      const float* __restrict__ W_fb,
                      const float* __restrict__ bias,
                      float* __restrict__ out) {
    // z-accumulation ring: ring[slot][i] accumulates sum_{k>=2..} W_k h contributions
    __shared__ __align__(16) float ring[RING * RDIM];   // 54080 B
    __shared__ __align__(16) float cur_h[RDIM];

    const int b = blockIdx.x;
    const int t = threadIdx.x;

    // zero the ring (initial states are zero => zero contributions)
    for (int idx = t; idx < RING * RDIM; idx += 256) ring[idx] = 0.0f;

    const bool active = (t < 200);
    const int k       = t / 40;          // tap index 0..4 (valid for t<200)
    const int p       = t % 40;          // i-pair index
    const int i0      = 2 * p;

    int tau = 0;
    if (active) {
        const int taus[5] = {1, 4, 24, 96, 168};
        tau = taus[k];
    }
    const bool is_fin = (t < 40);        // finalize threads own tap k=0 (tau=1)

    // ---- preload weights: W_fb[k][i0][:] and W_fb[k][i0+1][:] into registers
    float w0[RDIM], w1[RDIM];
    if (active) {
        const float4* r0 = (const float4*)(W_fb + (size_t)(k * RDIM + i0) * RDIM);
        const float4* r1 = (const float4*)(W_fb + (size_t)(k * RDIM + i0 + 1) * RDIM);
        #pragma unroll
        for (int j4 = 0; j4 < RDIM / 4; ++j4) {
            float4 a = r0[j4];
            float4 c = r1[j4];
            w0[4*j4+0] = a.x; w0[4*j4+1] = a.y; w0[4*j4+2] = a.z; w0[4*j4+3] = a.w;
            w1[4*j4+0] = c.x; w1[4*j4+1] = c.y; w1[4*j4+2] = c.z; w1[4*j4+3] = c.w;
        }
    }

    // finalize-thread state
    float win0 = 0.f, win1 = 0.f, bi0 = 0.f, bi1 = 0.f;
    float hprev0 = 0.f, hprev1 = 0.f;
    float u1_0 = 0.f, u1_1 = 0.f;        // W_1 h_{s-1} contribution (registers)
    float zpre0 = 0.f, zpre1 = 0.f;      // prefetched ring value for this step
    float xn = 0.f;                      // prefetched x[b][s]
    const float* xb   = x + (size_t)b * SEQ;
    float* outb       = out + (size_t)b * SEQ * RDIM;
    if (is_fin) {
        win0 = W_in[i0]; win1 = W_in[i0 + 1];
        bi0  = bias[i0]; bi1  = bias[i0 + 1];
        xn   = xb[0];
    }

    int c169 = 0;   // s % 169
    __syncthreads();

    #pragma unroll 1
    for (int s = 0; s < SEQ; ++s) {
        // ---- finalize h_s (threads 0..39, one i-pair each) ----
        if (is_fin) {
            float z0 = u1_0 + zpre0 + bi0 + xn * win0;
            float z1 = u1_1 + zpre1 + bi1 + xn * win1;
            float h0 = OMLEAK * hprev0 + LEAK * fast_tanh(z0);
            float h1 = OMLEAK * hprev1 + LEAK * fast_tanh(z1);
            hprev0 = h0; hprev1 = h1;
            ((float2*)cur_h)[p] = make_float2(h0, h1);
            // zero the consumed ring slot (slot s%169), safe: nobody writes it this step
            ((float2*)(ring + c169 * RDIM))[p] = make_float2(0.f, 0.f);
            // emit output
            float2 o; o.x = h0; o.y = h1;
            ((float2*)(outb + (size_t)s * RDIM))[p] = o;
        }
        __syncthreads();

        // ---- phase 1: u_k = W_k * h_s for all 5 taps (threads 0..199) ----
        if (active) {
            float a0 = 0.f, a1 = 0.f, a2 = 0.f, a3 = 0.f;   // partials for i0
            float c0 = 0.f, c1 = 0.f, c2 = 0.f, c3 = 0.f;   // partials for i0+1
            const float4* hv = (const float4*)cur_h;
            #pragma unroll
            for (int j4 = 0; j4 < RDIM / 4; ++j4) {
                float4 h4 = hv[j4];
                a0 = fmaf(w0[4*j4+0], h4.x, a0);
                a1 = fmaf(w0[4*j4+1], h4.y, a1);
                a2 = fmaf(w0[4*j4+2], h4.z, a2);
                a3 = fmaf(w0[4*j4+3], h4.w, a3);
                c0 = fmaf(w1[4*j4+0], h4.x, c0);
                c1 = fmaf(w1[4*j4+1], h4.y, c1);
                c2 = fmaf(w1[4*j4+2], h4.z, c2);
                c3 = fmaf(w1[4*j4+3], h4.w, c3);
            }
            float u0 = (a0 + a1) + (a2 + a3);
            float u1 = (c0 + c1) + (c2 + c3);

            if (k == 0) {
                // tau=1 contribution stays in registers for next finalize
                u1_0 = u0; u1_1 = u1;
                // prefetch ring slot for step s+1 (stable: last writer was step s-3)
                int nslot = c169 + 1; if (nslot >= RING) nslot = 0;
                float2 zp = ((const float2*)(ring + nslot * RDIM))[p];
                zpre0 = zp.x; zpre1 = zp.y;
                // prefetch next x
                int sn = s + 1; if (sn >= SEQ) sn = SEQ - 1;
                xn = xb[sn];
            } else {
                // accumulate into ring slot (s + tau) % 169
                int slot = c169 + tau; if (slot >= RING) slot -= RING;
                float2 r = ((const float2*)(ring + slot * RDIM))[p];
                r.x += u0; r.y += u1;
                ((float2*)(ring + slot * RDIM))[p] = r;
            }
        }
        c169 += 1; if (c169 >= RING) c169 = 0;
        __syncthreads();
    }
}

extern "C" void kernel_launch(void* const* d_in, const int* in_sizes, int n_in,
                              void* d_out, int out_size, void* d_ws, size_t ws_size,
                              hipStream_t stream) {
    const float* x    = (const float*)d_in[0];   // (64, 8192, 1)
    const float* W_in = (const float*)d_in[1];   // (80, 1)
    const float* W_fb = (const float*)d_in[2];   // (5, 80, 80)
    const float* bias = (const float*)d_in[3];   // (80,)
    float* out        = (float*)d_out;           // (64, 8192, 80)

    reservoir_kernel<<<BATCH, 256, 0, stream>>>(x, W_in, W_fb, bias, out);
}